// Round 6
// baseline (105.568 us; speedup 1.0000x reference)
//
#include <hip/hip_runtime.h>

// DTW wavefront kernel for MI355X (gfx950). Round 6.
// B=32, N=32, D=12, P=32, L=1024, L_OUT=32, RHO=1 => w=1.
// D[i,j] = c[i,j] + min3(D[i-1,j-1], D[i-1,j], D[i,j-1]).
// r4=r5=45.6us => producer-bound (barrier lockstep = max(Tp,Tc)).
// r6: producer: 4x mfma_32x32x16_bf16 (was 16x 16x16x32), double-buffered
// x prefetch regs (no vmcnt drain at barrier), reg-independent write addr.
// consumer: RSTR=262 -> read bank = 2*li (conflict-free b64 pairs);
// ring/jcur/store logic bit-identical to r5 (validated).

#define BIGF  1e30f
#define LL    1024
#define LOUT  32
#define RSTR  262        // ring 256 + pad; 262 % 32 = 6 -> diagonal banks
#define RINGM 255
#define NCH   16

using v4f    = __attribute__((ext_vector_type(4))) float;
using f2v    = __attribute__((ext_vector_type(2))) float;
using f32x16 = __attribute__((ext_vector_type(16))) float;
using s16x8  = __attribute__((ext_vector_type(8))) short;   // 8 bf16

__device__ __forceinline__ float wshr1(float v) {
    // whole-wave shift: lane i <- lane i-1 (lane 0 <- old=0), VALU dpp
    int r = __builtin_amdgcn_update_dpp(0, __float_as_int(v), 0x138 /*wave_shr:1*/,
                                        0xF, 0xF, false);
    return __int_as_float(r);
}

__device__ __forceinline__ short f2bf(float f) {   // fp32 -> bf16 RNE
    unsigned u = __float_as_uint(f);
    u += 0x7FFF + ((u >> 16) & 1);
    return (short)(u >> 16);
}

__device__ __forceinline__ v4f load_quad(const float* crow, int& roff) {
    f2v a = *(const f2v*)(crow + roff);
    f2v b = *(const f2v*)(crow + ((roff + 2) & RINGM));
    roff = (roff + 4) & RINGM;
    v4f r = {a.x, a.y, b.x, b.y};
    return r;
}

// One super-step: 4 columns, lane-lag 4. Cross-lane = 4 dpp, off the
// per-column chain. Identical DP semantics to r5 (validated).
template<bool STORE, bool FIX>
__device__ __forceinline__ void sstep(v4f& O, float& Dloc, float& Uc, v4f c,
                                      bool l0, int& jcur, float* lds_out,
                                      int outbase) {
    float U0 = wshr1(O.x), U1 = wshr1(O.y), U2 = wshr1(O.z), U3 = wshr1(O.w);
    if (l0) { U0 = BIGF; U1 = BIGF; U2 = BIGF; U3 = BIGF; }  // row -1 boundary
    float Um0 = fminf(Uc, U0);
    float Um1 = fminf(U0, U1);
    float Um2 = fminf(U1, U2);
    float Um3 = fminf(U2, U3);
    if (FIX) Um3 = l0 ? 0.0f : Um3;     // virtual D[-1,-1]=0 -> D[0,0]=c[0,0]
    Uc = U3;
    float D0 = c.x + fminf(Um0, Dloc);
    float D1 = c.y + fminf(Um1, D0);
    float D2 = c.z + fminf(Um2, D1);
    float D3 = c.w + fminf(Um3, D2);
    Dloc = D3;
    O.x = D0; O.y = D1; O.z = D2; O.w = D3;
    if (STORE) {
        unsigned j0 = (unsigned)(jcur - (LL - LOUT));   // wraps for jcur<992
        if (j0 + 0u < 32u) lds_out[outbase + (j0 + 0u)] = D0;
        if (j0 + 1u < 32u) lds_out[outbase + (j0 + 1u)] = D1;
        if (j0 + 2u < 32u) lds_out[outbase + (j0 + 2u)] = D2;
        if (j0 + 3u < 32u) lds_out[outbase + (j0 + 3u)] = D3;
        jcur += 4;
    }
}

// One group = 16 super-steps = 64 columns of wavefront advance.
// 4 primed quads + 12 refills: max ring pos read in group g stays < the
// slot produce(g+1) writes (same col-space schedule as r5, validated).
template<bool STORE, bool FIX0>
__device__ __forceinline__ void run_group(v4f& O, float& Dloc, float& Uc,
                                          const float* crow, int& roff, bool l0,
                                          int& jcur, float* lds_out, int outbase) {
    v4f q[4];
#pragma unroll
    for (int k = 0; k < 4; ++k) q[k] = load_quad(crow, roff);
    sstep<STORE, FIX0 >(O, Dloc, Uc, q[0], l0, jcur, lds_out, outbase); q[0] = load_quad(crow, roff);
    sstep<STORE, false>(O, Dloc, Uc, q[1], l0, jcur, lds_out, outbase); q[1] = load_quad(crow, roff);
    sstep<STORE, false>(O, Dloc, Uc, q[2], l0, jcur, lds_out, outbase); q[2] = load_quad(crow, roff);
    sstep<STORE, false>(O, Dloc, Uc, q[3], l0, jcur, lds_out, outbase); q[3] = load_quad(crow, roff);
#pragma unroll
    for (int rep = 0; rep < 2; ++rep) {
        sstep<STORE, false>(O, Dloc, Uc, q[0], l0, jcur, lds_out, outbase); q[0] = load_quad(crow, roff);
        sstep<STORE, false>(O, Dloc, Uc, q[1], l0, jcur, lds_out, outbase); q[1] = load_quad(crow, roff);
        sstep<STORE, false>(O, Dloc, Uc, q[2], l0, jcur, lds_out, outbase); q[2] = load_quad(crow, roff);
        sstep<STORE, false>(O, Dloc, Uc, q[3], l0, jcur, lds_out, outbase); q[3] = load_quad(crow, roff);
    }
    sstep<STORE, false>(O, Dloc, Uc, q[0], l0, jcur, lds_out, outbase);
    sstep<STORE, false>(O, Dloc, Uc, q[1], l0, jcur, lds_out, outbase);
    sstep<STORE, false>(O, Dloc, Uc, q[2], l0, jcur, lds_out, outbase);
    sstep<STORE, false>(O, Dloc, Uc, q[3], l0, jcur, lds_out, outbase);
}

__global__ __launch_bounds__(128) void dtw_kernel(const float* __restrict__ x,
                                                  const float* __restrict__ patts,
                                                  float* __restrict__ out) {
    __shared__ alignas(16) float cbuf[64 * RSTR];   // 65.5 KB: 64 rows x 256 ring
    __shared__ float x2s[LL];                        // 4 KB
    __shared__ float p2s[64];
    __shared__ float lds_out[2 * 32 * LOUT];         // 8 KB

    const int tid  = threadIdx.x;
    const int wid  = tid >> 6;        // 0 = producer, 1 = consumer
    const int lane = tid & 63;
    const int li   = lane & 31;
    const int half = lane >> 5;
    const int c32  = lane & 31;       // producer: col-in-tile / A row
    const int hp   = lane >> 5;       // producer: k-half for 32x32x16 frags
    const bool l0  = (li == 0);
    const int blk = blockIdx.x;
    const int b   = blk >> 4;
    const int n0  = (blk & 15) << 1;

    const float* __restrict__ xb = x + b * (12 * LL);

    // ---- prefill ring with 0.0 (BIG-propagation in ramp; exact) ----
    {
        v4f z = {0.f, 0.f, 0.f, 0.f};
#pragma unroll 1
        for (int k = 0; k < 33; ++k) {
            int idx = tid + 128 * k;             // v4f index, 4192 total
            if (idx < (64 * RSTR) / 4) *(v4f*)(&cbuf[4 * idx]) = z;
        }
    }

    // ---- x2s[j] = sum_d x[b][d][j]^2, split across both waves ----
#pragma unroll 1
    for (int k = 0; k < 8; k += 2) {
        int col0 = (wid * 8 + k) * 64 + lane;
        int col1 = col0 + 64;
        float a0 = 0.f, a1 = 0.f;
#pragma unroll
        for (int d = 0; d < 12; ++d) {
            float v = xb[d * LL + col0]; a0 += v * v;
            float w = xb[d * LL + col1]; a1 += w * w;
        }
        x2s[col0] = a0; x2s[col1] = a1;
    }

    // ---- producer-only setup ----
    s16x8 afrag[2];                 // A[row=c32][k=8*hp+e] per problem
    float p2l[2][16];               // p2 for C-frag rows
    int   rb[2][16];                // row * RSTR write bases
    float xpre[2][2][8];            // double-buffered x B-frag staging
    if (wid == 0) {
        {   // p2s[r], r = half*32 + li
            const float* pn = patts + (n0 + half) * (12 * 32);
            float acc = 0.f;
#pragma unroll
            for (int d = 0; d < 12; ++d) { float v = pn[d * 32 + li]; acc += v * v; }
            p2s[lane] = acc;
        }
#pragma unroll
        for (int mt = 0; mt < 2; ++mt) {
            const float* pm = patts + (n0 + mt) * (12 * 32);
#pragma unroll
            for (int e = 0; e < 8; ++e) {
                int d = 8 * hp + e;
                afrag[mt][e] = f2bf(d < 12 ? pm[d * 32 + c32] : 0.f);
            }
#pragma unroll
            for (int reg = 0; reg < 16; ++reg) {
                int rowin = (reg & 3) + 8 * (reg >> 2) + 4 * hp;   // C/D row map
                p2l[mt][reg] = p2s[32 * mt + rowin];  // intra-wave LDS RAW: safe
                rb[mt][reg]  = (32 * mt + rowin) * RSTR;
            }
        }
        // zero-init + load x chunk 0 into buffer 0
#pragma unroll
        for (int p = 0; p < 2; ++p)
#pragma unroll
            for (int ct = 0; ct < 2; ++ct)
#pragma unroll
                for (int e = 0; e < 8; ++e) xpre[p][ct][e] = 0.f;
#pragma unroll
        for (int ct = 0; ct < 2; ++ct)
#pragma unroll
            for (int e = 0; e < 8; ++e) {
                int d = 8 * hp + e;
                if (d < 12) xpre[0][ct][e] = xb[d * LL + 32 * ct + c32];
            }
    }

    auto produce = [&](int c) {
        const int p = c & 1;
        s16x8 bfrag[2];
#pragma unroll
        for (int ct = 0; ct < 2; ++ct)
#pragma unroll
            for (int e = 0; e < 8; ++e) bfrag[ct][e] = f2bf(xpre[p][ct][e]);
        // prefetch chunk c+1 into the other buffer (consumed next call;
        // vmcnt drained at a barrier one full chunk later -> latency hidden)
        if (c + 1 < NCH) {
            const int j1 = (c + 1) * 64;
#pragma unroll
            for (int ct = 0; ct < 2; ++ct)
#pragma unroll
                for (int e = 0; e < 8; ++e) {
                    int d = 8 * hp + e;
                    if (d < 12) xpre[p ^ 1][ct][e] = xb[d * LL + j1 + 32 * ct + c32];
                }
        }
        const int j0 = c * 64;
#pragma unroll
        for (int ct = 0; ct < 2; ++ct) {
            float x2v = x2s[j0 + 32 * ct + c32];
            int pos = (j0 + 32 * ct + c32 + 3) & RINGM;   // +3 ring rot (r5)
#pragma unroll
            for (int mt = 0; mt < 2; ++mt) {
                f32x16 z = {0.f,0.f,0.f,0.f,0.f,0.f,0.f,0.f,
                            0.f,0.f,0.f,0.f,0.f,0.f,0.f,0.f};
                f32x16 acc = __builtin_amdgcn_mfma_f32_32x32x16_bf16(
                                 afrag[mt], bfrag[ct], z, 0, 0, 0);
#pragma unroll
                for (int reg = 0; reg < 16; ++reg)
                    cbuf[rb[mt][reg] + pos] =
                        fmaf(-2.0f, acc[reg], p2l[mt][reg] + x2v);
            }
        }
    };

    // ---- consumer DP state (bit-identical to r5) ----
    v4f   O    = {BIGF, BIGF, BIGF, BIGF};
    float Dloc = BIGF, Uc = BIGF;
    int   roff = (-(4 * li)) & RINGM;
    int   jcur = 957 - 4 * li;
    const float* crow = cbuf + lane * RSTR;
    const int outbase = half * (32 * LOUT) + li * LOUT;

    __syncthreads();                 // prefill + x2s ready
    if (wid == 0) produce(0);
    __syncthreads();                 // chunk 0 ready

#pragma unroll 1
    for (int g = 0; g < 18; ++g) {
        if (wid == 0) {
            if (g <= 14) produce(g + 1);
        } else {
            if (g == 0)
                run_group<false, true >(O, Dloc, Uc, crow, roff, l0, jcur, lds_out, outbase);
            else if (g < 15)
                run_group<false, false>(O, Dloc, Uc, crow, roff, l0, jcur, lds_out, outbase);
            else
                run_group<true,  false>(O, Dloc, Uc, crow, roff, l0, jcur, lds_out, outbase);
        }
        __syncthreads();
    }

    // ---- coalesced flush: 2048 floats, 128 threads ----
    float* ob = out + blk * (2 * 32 * LOUT);
#pragma unroll
    for (int r = 0; r < 4; ++r) {
        int idx = r * 512 + tid * 4;
        v4f v = *(const v4f*)(&lds_out[idx]);
        *(v4f*)(ob + idx) = v;
    }
}

extern "C" void kernel_launch(void* const* d_in, const int* in_sizes, int n_in,
                              void* d_out, int out_size, void* d_ws, size_t ws_size,
                              hipStream_t stream) {
    const float* x     = (const float*)d_in[0];   // [32,12,1024] f32
    const float* patts = (const float*)d_in[1];   // [32,12,32]   f32
    float* out         = (float*)d_out;           // [32,32,32,32] f32
    dtw_kernel<<<dim3(512), dim3(128), 0, stream>>>(x, patts, out);
}

// Round 8
// 85.948 us; speedup vs baseline: 1.2283x; 1.2283x over previous
//
#include <hip/hip_runtime.h>

// DTW via min-plus scan for MI355X (gfx950). Round 8.
// B=32, N=32, D=12, P=32, L=1024, L_OUT=32, RHO=1 => w=1.
// Per row i: D[j] = c[j] + min(a[j], D[j-1]) is a min-plus prefix scan:
//   S[j] = prefix_sum(c[i,:]),  D[j] = S[j] + prefix_min_k(a[k] - S[k-1]),
//   a[k] = min(D_prev[k-1], D_prev[k]),  S[-1] = 0.
// Lanes = columns (16 cols/lane, one wave per (b,n) problem). Rows serial.
// Cost never materialized: S[i,j] = p2[i]*(j+1) + SX2[j] - 2*sum_d p[i,d]*SXd[j]
// with SXd/SX2 = inclusive prefix sums of x / x^2. Full fp32.
// r8 vs r7 (absmax 1.9e5): ALL scans now __shfl_up Hillis-Steele (r1-validated
// primitive); single shifts via update_dpp(0,v,0x138) (r2-r6-validated).
// The r7 row_shr/row_bcast DPP scan path is suspected broken and removed.

#define BIGF 1e30f
#define LL   1024
#define LOUT 32

using v4f = __attribute__((ext_vector_type(4))) float;

// validated r2-r6: whole-wave shift right 1 lane; lane 0 <- 0
__device__ __forceinline__ float wshr1z(float v) {
    return __int_as_float(__builtin_amdgcn_update_dpp(
        0, __float_as_int(v), 0x138 /*wave_shr:1*/, 0xF, 0xF, false));
}

// inclusive 64-lane scans via __shfl_up (Hillis-Steele, explicit selects)
__device__ __forceinline__ float scan_min64(float t, int lane) {
#pragma unroll
    for (int d = 1; d < 64; d <<= 1) {
        float o = __shfl_up(t, (unsigned)d, 64);
        t = (lane >= d) ? fminf(t, o) : t;
    }
    return t;
}
__device__ __forceinline__ float scan_add64(float t, int lane) {
#pragma unroll
    for (int d = 1; d < 64; d <<= 1) {
        float o = __shfl_up(t, (unsigned)d, 64);
        t += (lane >= d) ? o : 0.0f;
    }
    return t;
}

__global__ __launch_bounds__(64, 1)   // 1 wave/block -> full VGPR budget
void dtw_kernel(const float* __restrict__ x, const float* __restrict__ patts,
                float* __restrict__ out) {
    __shared__ float pT[32 * 12];   // -2*patts[n], layout [i][d]
    __shared__ float p2s[32];

    const int lane = threadIdx.x;          // lane owns cols [16*lane, 16*lane+16)
    const bool l0  = (lane == 0);
    const int blk  = blockIdx.x;           // 0..1023 = (b,n)
    const int b    = blk >> 5, n = blk & 31;
    const float* __restrict__ xb = x + b * (12 * LL);
    const float* __restrict__ pn = patts + n * (12 * 32);

    // ---- patts transpose (scaled by -2) + p2, lanes 0..31 ----
    if (lane < 32) {
        float s2 = 0.f;
#pragma unroll
        for (int d = 0; d < 12; ++d) {
            float v = pn[d * 32 + lane];
            s2 = fmaf(v, v, s2);
            pT[lane * 12 + d] = -2.0f * v;
        }
        p2s[lane] = s2;
    }

    // ---- x slice -> regs (coalesced 16B/lane) ----
    float SX[12][16];
#pragma unroll
    for (int d = 0; d < 12; ++d) {
#pragma unroll
        for (int c = 0; c < 4; ++c) {
            v4f v = *(const v4f*)(xb + d * LL + 16 * lane + 4 * c);
            SX[d][4*c+0] = v.x; SX[d][4*c+1] = v.y;
            SX[d][4*c+2] = v.z; SX[d][4*c+3] = v.w;
        }
    }
    float SX2[16];
#pragma unroll
    for (int k = 0; k < 16; ++k) {
        float a = 0.f;
#pragma unroll
        for (int d = 0; d < 12; ++d) a = fmaf(SX[d][k], SX[d][k], a);
        SX2[k] = a;
    }
    // ---- inclusive prefix sums: intra-lane serial + cross-lane shfl scan ----
#pragma unroll
    for (int d = 0; d < 12; ++d) {
#pragma unroll
        for (int k = 1; k < 16; ++k) SX[d][k] += SX[d][k-1];
        float tot = SX[d][15];
        float ex  = scan_add64(tot, lane) - tot;   // exclusive lane offset
#pragma unroll
        for (int k = 0; k < 16; ++k) SX[d][k] += ex;
    }
    {
#pragma unroll
        for (int k = 1; k < 16; ++k) SX2[k] += SX2[k-1];
        float tot = SX2[15];
        float ex  = scan_add64(tot, lane) - tot;
#pragma unroll
        for (int k = 0; k < 16; ++k) SX2[k] += ex;
    }
    float jp1[16];
#pragma unroll
    for (int k = 0; k < 16; ++k) jp1[k] = (float)(16 * lane + k + 1);

    __syncthreads();

    // ---- row 0: D = S (prefix sum of cost row 0) ----
    float pv[12], p2u;
#pragma unroll
    for (int d = 0; d < 12; ++d) pv[d] = pT[d];
    p2u = p2s[0];

    float Dp[16];
    {
        float S[16];
#pragma unroll
        for (int k = 0; k < 16; ++k) S[k] = fmaf(p2u, jp1[k], SX2[k]);
#pragma unroll
        for (int d = 0; d < 12; ++d)
#pragma unroll
            for (int k = 0; k < 16; ++k) S[k] = fmaf(pv[d], SX[d][k], S[k]);
#pragma unroll
        for (int k = 0; k < 16; ++k) Dp[k] = S[k];
        if (lane >= 62) {
            float* ob = out + blk * (32 * LOUT) + (lane - 62) * 16;
#pragma unroll
            for (int c = 0; c < 4; ++c) {
                v4f v = {Dp[4*c], Dp[4*c+1], Dp[4*c+2], Dp[4*c+3]};
                *(v4f*)(ob + 4 * c) = v;
            }
        }
    }
#pragma unroll
    for (int d = 0; d < 12; ++d) pv[d] = pT[12 + d];
    p2u = p2s[1];

    // ---- rows 1..31 ----
#pragma unroll 1
    for (int i = 1; i < 32; ++i) {
        // prefetch row i+1 params (LDS broadcast reads, off the chain)
        const int ip = (i + 1 < 32) ? i + 1 : 31;
        float pvn[12], p2n;
#pragma unroll
        for (int d = 0; d < 12; ++d) pvn[d] = pT[ip * 12 + d];
        p2n = p2s[ip];

        // S[i, k] for this lane's 16 columns (independent of Dp)
        float S[16];
#pragma unroll
        for (int k = 0; k < 16; ++k) S[k] = fmaf(p2u, jp1[k], SX2[k]);
#pragma unroll
        for (int d = 0; d < 12; ++d)
#pragma unroll
            for (int k = 0; k < 16; ++k) S[k] = fmaf(pv[d], SX[d][k], S[k]);

        // neighbor boundary values (validated primitive)
        float dsh = wshr1z(Dp[15]); dsh = l0 ? BIGF : dsh;  // D_prev[j-1] at k=0
        float se  = wshr1z(S[15]);                          // S[j-1] at k=0 (lane0->0)

        // z[k] = a[k] - S[k-1]; intra-lane inclusive min-scan m
        float m[16];
        m[0] = fminf(dsh, Dp[0]) - se;
#pragma unroll
        for (int k = 1; k < 16; ++k) {
            float a = fminf(Dp[k-1], Dp[k]);
            m[k] = fminf(m[k-1], a - S[k-1]);
        }
        // cross-lane exclusive prefix-min of lane totals
        float t  = scan_min64(m[15], lane);
        float te = wshr1z(t); te = l0 ? BIGF : te;
        // D = S + min(te, m)
#pragma unroll
        for (int k = 0; k < 16; ++k) Dp[k] = S[k] + fminf(te, m[k]);

        if (lane >= 62) {
            float* ob = out + blk * (32 * LOUT) + (lane - 62) * 16;
#pragma unroll
            for (int c = 0; c < 4; ++c) {
                v4f v = {Dp[4*c], Dp[4*c+1], Dp[4*c+2], Dp[4*c+3]};
                *(v4f*)(ob + i * 32 + 4 * c) = v;
            }
        }
#pragma unroll
        for (int d = 0; d < 12; ++d) pv[d] = pvn[d];
        p2u = p2n;
    }
}

extern "C" void kernel_launch(void* const* d_in, const int* in_sizes, int n_in,
                              void* d_out, int out_size, void* d_ws, size_t ws_size,
                              hipStream_t stream) {
    const float* x     = (const float*)d_in[0];   // [32,12,1024] f32
    const float* patts = (const float*)d_in[1];   // [32,12,32]   f32
    float* out         = (float*)d_out;           // [32,32,32,32] f32
    dtw_kernel<<<dim3(1024), dim3(64), 0, stream>>>(x, patts, out);
}

// Round 9
// 81.342 us; speedup vs baseline: 1.2978x; 1.0566x over previous
//
#include <hip/hip_runtime.h>

// DTW via min-plus scan for MI355X (gfx950). Round 9.
// B=32, N=32, D=12, P=32, L=1024, L_OUT=32, RHO=1 => w=1.
// Per row i: D[j] = c[j] + min(a[j], D[j-1]) is a min-plus prefix scan:
//   S[j] = prefix_sum(c[i,:]),  D[j] = S[j] + prefix_min_k(a[k] - S[k-1]),
//   a[k] = min(D_prev[k-1], D_prev[k]),  S[-1] = 0.
// Lanes = columns (16 cols/lane, one wave per (b,n) problem). Rows serial.
// S[i,j] = p2[i]*(j+1) + SX2[j] - 2*sum_d p[i,d]*SXd[j], prefix sums of x.
// r9 vs r8 (pass, kernel ~35us): (1) per-row scan = 4x dpp row_shr (old=self)
// + readlane(15/31/47) row-combine — no ds_bpermute, no row_bcast (r7's
// suspected bug was row_bcast with row_mask 0xF); (2) next row's S computed
// between scan issue and scan use (fills the chain with independent fmas).

#define BIGF 1e30f
#define LL   1024
#define LOUT 32

using v4f = __attribute__((ext_vector_type(4))) float;

template<int CTRL>
__device__ __forceinline__ float dpp_self(float v) {   // invalid lanes keep own
    return __int_as_float(__builtin_amdgcn_update_dpp(
        __float_as_int(v), __float_as_int(v), CTRL, 0xF, 0xF, false));
}
// validated r2-r8: whole-wave shift right 1 lane; lane 0 <- 0
__device__ __forceinline__ float wshr1z(float v) {
    return __int_as_float(__builtin_amdgcn_update_dpp(
        0, __float_as_int(v), 0x138 /*wave_shr:1*/, 0xF, 0xF, false));
}
__device__ __forceinline__ float rdlane(float v, int l) {
    return __int_as_float(__builtin_amdgcn_readlane(__float_as_int(v), l));
}

// inclusive wave64 min-scan: 4 dpp row_shr hops (within 16-lane rows) +
// readlane row-combine (no row_bcast, no bpermute)
__device__ __forceinline__ float scan_min64_fast(float t, int lane) {
    t = fminf(t, dpp_self<0x111>(t));   // row_shr:1
    t = fminf(t, dpp_self<0x112>(t));   // row_shr:2
    t = fminf(t, dpp_self<0x114>(t));   // row_shr:4
    t = fminf(t, dpp_self<0x118>(t));   // row_shr:8
    float r0 = rdlane(t, 15), r1 = rdlane(t, 31), r2 = rdlane(t, 47);
    t = fminf(t, (lane >= 16) ? r0 : BIGF);
    t = fminf(t, (lane >= 32) ? r1 : BIGF);
    t = fminf(t, (lane >= 48) ? r2 : BIGF);
    return t;
}

// setup-only (off critical path): r8-validated shfl_up add scan
__device__ __forceinline__ float scan_add64(float t, int lane) {
#pragma unroll
    for (int d = 1; d < 64; d <<= 1) {
        float o = __shfl_up(t, (unsigned)d, 64);
        t += (lane >= d) ? o : 0.0f;
    }
    return t;
}

__global__ __launch_bounds__(64, 1)   // 1 wave/block -> full VGPR budget
void dtw_kernel(const float* __restrict__ x, const float* __restrict__ patts,
                float* __restrict__ out) {
    __shared__ float pT[32 * 12];   // -2*patts[n], layout [i][d]
    __shared__ float p2s[32];

    const int lane = threadIdx.x;          // lane owns cols [16*lane, 16*lane+16)
    const bool l0  = (lane == 0);
    const int blk  = blockIdx.x;           // 0..1023 = (b,n)
    const int b    = blk >> 5, n = blk & 31;
    const float* __restrict__ xb = x + b * (12 * LL);
    const float* __restrict__ pn = patts + n * (12 * 32);

    // ---- patts transpose (scaled by -2) + p2, lanes 0..31 ----
    if (lane < 32) {
        float s2 = 0.f;
#pragma unroll
        for (int d = 0; d < 12; ++d) {
            float v = pn[d * 32 + lane];
            s2 = fmaf(v, v, s2);
            pT[lane * 12 + d] = -2.0f * v;
        }
        p2s[lane] = s2;
    }

    // ---- x slice -> regs (coalesced 16B/lane) ----
    float SX[12][16];
#pragma unroll
    for (int d = 0; d < 12; ++d) {
#pragma unroll
        for (int c = 0; c < 4; ++c) {
            v4f v = *(const v4f*)(xb + d * LL + 16 * lane + 4 * c);
            SX[d][4*c+0] = v.x; SX[d][4*c+1] = v.y;
            SX[d][4*c+2] = v.z; SX[d][4*c+3] = v.w;
        }
    }
    float SX2[16];
#pragma unroll
    for (int k = 0; k < 16; ++k) {
        float a = 0.f;
#pragma unroll
        for (int d = 0; d < 12; ++d) a = fmaf(SX[d][k], SX[d][k], a);
        SX2[k] = a;
    }
    // ---- inclusive prefix sums: intra-lane serial + cross-lane shfl scan ----
#pragma unroll
    for (int d = 0; d < 12; ++d) {
#pragma unroll
        for (int k = 1; k < 16; ++k) SX[d][k] += SX[d][k-1];
        float tot = SX[d][15];
        float ex  = scan_add64(tot, lane) - tot;   // exclusive lane offset
#pragma unroll
        for (int k = 0; k < 16; ++k) SX[d][k] += ex;
    }
    {
#pragma unroll
        for (int k = 1; k < 16; ++k) SX2[k] += SX2[k-1];
        float tot = SX2[15];
        float ex  = scan_add64(tot, lane) - tot;
#pragma unroll
        for (int k = 0; k < 16; ++k) SX2[k] += ex;
    }
    float jp1[16];
#pragma unroll
    for (int k = 0; k < 16; ++k) jp1[k] = (float)(16 * lane + k + 1);

    __syncthreads();

    // ---- row 0: D = S(row 0) ----
    float pv[12], p2u;
#pragma unroll
    for (int d = 0; d < 12; ++d) pv[d] = pT[d];
    p2u = p2s[0];

    float S[16], Dp[16];
#pragma unroll
    for (int k = 0; k < 16; ++k) S[k] = fmaf(p2u, jp1[k], SX2[k]);
#pragma unroll
    for (int d = 0; d < 12; ++d)
#pragma unroll
        for (int k = 0; k < 16; ++k) S[k] = fmaf(pv[d], SX[d][k], S[k]);
#pragma unroll
    for (int k = 0; k < 16; ++k) Dp[k] = S[k];
    if (lane >= 62) {
        float* ob = out + blk * (32 * LOUT) + (lane - 62) * 16;
#pragma unroll
        for (int c = 0; c < 4; ++c) {
            v4f v = {Dp[4*c], Dp[4*c+1], Dp[4*c+2], Dp[4*c+3]};
            *(v4f*)(ob + 4 * c) = v;
        }
    }

    // ---- S for row 1 (pipelined: loop iteration i consumes S(row i)) ----
#pragma unroll
    for (int d = 0; d < 12; ++d) pv[d] = pT[12 + d];
    p2u = p2s[1];
#pragma unroll
    for (int k = 0; k < 16; ++k) S[k] = fmaf(p2u, jp1[k], SX2[k]);
#pragma unroll
    for (int d = 0; d < 12; ++d)
#pragma unroll
        for (int k = 0; k < 16; ++k) S[k] = fmaf(pv[d], SX[d][k], S[k]);

    // ---- rows 1..31 ----
#pragma unroll 1
    for (int i = 1; i < 32; ++i) {
        const int ip = (i + 1 < 32) ? i + 1 : 31;
        float pvn[12];
#pragma unroll
        for (int d = 0; d < 12; ++d) pvn[d] = pT[ip * 12 + d];
        float p2n = p2s[ip];

        // boundary values from the left neighbor (validated primitive)
        float dsh = wshr1z(Dp[15]); dsh = l0 ? BIGF : dsh;  // D_prev[j-1] at k=0
        float se  = wshr1z(S[15]);                          // S[j-1] at k=0 (lane0->0)

        // z[k] = a[k] - S[k-1]; intra-lane inclusive min-scan m
        float m[16];
        m[0] = fminf(dsh, Dp[0]) - se;
#pragma unroll
        for (int k = 1; k < 16; ++k)
            m[k] = fminf(m[k-1], fminf(Dp[k-1], Dp[k]) - S[k-1]);

        // cross-lane inclusive min-scan of lane totals (fast DPP+readlane)
        float t = scan_min64_fast(m[15], lane);

        // ---- next row's S: independent of t -> fills the scan latency ----
        float Sn[16];
#pragma unroll
        for (int k = 0; k < 16; ++k) Sn[k] = fmaf(p2n, jp1[k], SX2[k]);
#pragma unroll
        for (int d = 0; d < 12; ++d)
#pragma unroll
            for (int k = 0; k < 16; ++k) Sn[k] = fmaf(pvn[d], SX[d][k], Sn[k]);

        float te = wshr1z(t); te = l0 ? BIGF : te;          // exclusive
#pragma unroll
        for (int k = 0; k < 16; ++k) Dp[k] = S[k] + fminf(te, m[k]);

        if (lane >= 62) {
            float* ob = out + blk * (32 * LOUT) + (lane - 62) * 16;
#pragma unroll
            for (int c = 0; c < 4; ++c) {
                v4f v = {Dp[4*c], Dp[4*c+1], Dp[4*c+2], Dp[4*c+3]};
                *(v4f*)(ob + i * 32 + 4 * c) = v;
            }
        }
#pragma unroll
        for (int k = 0; k < 16; ++k) S[k] = Sn[k];
    }
}

extern "C" void kernel_launch(void* const* d_in, const int* in_sizes, int n_in,
                              void* d_out, int out_size, void* d_ws, size_t ws_size,
                              hipStream_t stream) {
    const float* x     = (const float*)d_in[0];   // [32,12,1024] f32
    const float* patts = (const float*)d_in[1];   // [32,12,32]   f32
    float* out         = (float*)d_out;           // [32,32,32,32] f32
    dtw_kernel<<<dim3(1024), dim3(64), 0, stream>>>(x, patts, out);
}